// Round 5
// baseline (271.152 us; speedup 1.0000x reference)
//
#include <hip/hip_runtime.h>
#include <hip/hip_bf16.h>
#include <math.h>

#define B_   2
#define T_   2048
#define C_   1024
#define H_   16
#define D_   64
#define NCH  32
#define RD   32
#define TOPB 8

typedef __attribute__((ext_vector_type(8))) short bf16x8;
typedef __attribute__((ext_vector_type(4))) float f32x4;

static __device__ __forceinline__ unsigned short f2b(float f) {
    return __bfloat16_as_ushort(__float2bfloat16(f));
}

// ---------------------------------------------------------------------------
// cast x (f32) -> bf16, 8 elements per thread
// ---------------------------------------------------------------------------
__global__ __launch_bounds__(256) void cast_bf16_kernel(
    const float* __restrict__ in, unsigned short* __restrict__ out, int n8)
{
    const int i = blockIdx.x * blockDim.x + threadIdx.x;
    if (i >= n8) return;
    float4 a = ((const float4*)in)[i * 2];
    float4 b = ((const float4*)in)[i * 2 + 1];
    bf16x8 o;
    o[0] = (short)f2b(a.x); o[1] = (short)f2b(a.y);
    o[2] = (short)f2b(a.z); o[3] = (short)f2b(a.w);
    o[4] = (short)f2b(b.x); o[5] = (short)f2b(b.y);
    o[6] = (short)f2b(b.z); o[7] = (short)f2b(b.w);
    *(bf16x8*)&out[i * 8] = o;
}

// ---------------------------------------------------------------------------
// W [K][N] f32 -> Wt [N][K] bf16, 64x64 tiles via LDS
// ---------------------------------------------------------------------------
__global__ __launch_bounds__(256) void transpose_cast_kernel(
    const float* __restrict__ W, unsigned short* __restrict__ Wt, int K, int N)
{
    __shared__ float t[64][65];
    const int tid = threadIdx.x;
    const int n0 = blockIdx.x * 64, k0 = blockIdx.y * 64;
#pragma unroll
    for (int i = 0; i < 4; i++) {
        const int f = tid + i * 256;
        const int r = f >> 4, c4 = (f & 15) * 4;
        float4 v = *(const float4*)&W[(size_t)(k0 + r) * N + n0 + c4];
        t[r][c4 + 0] = v.x; t[r][c4 + 1] = v.y;
        t[r][c4 + 2] = v.z; t[r][c4 + 3] = v.w;
    }
    __syncthreads();
#pragma unroll
    for (int i = 0; i < 2; i++) {
        const int s = tid + i * 256;
        const int rn = s >> 3, ck8 = (s & 7) * 8;
        bf16x8 o;
#pragma unroll
        for (int j = 0; j < 8; j++) o[j] = (short)f2b(t[ck8 + j][rn]);
        *(bf16x8*)&Wt[(size_t)(n0 + rn) * K + k0 + ck8] = o;
    }
}

// ---------------------------------------------------------------------------
// bf16 MFMA GEMM (m97 structure): C = A[M,K] @ Bt[N,K]^T + bias
// ---------------------------------------------------------------------------
template <int MODE>
__global__ __launch_bounds__(256) void gemm_mfma(
    const unsigned short* __restrict__ A, const unsigned short* __restrict__ Bt,
    const float* __restrict__ bias, float* __restrict__ out,
    unsigned short* __restrict__ qp, unsigned short* __restrict__ kp,
    unsigned short* __restrict__ vp, int M, int N, int K)
{
    __shared__ unsigned short As[128 * 32];
    __shared__ unsigned short Bs[128 * 32];

    const int tid  = threadIdx.x;
    const int lane = tid & 63;
    const int wave = tid >> 6;
    const int lr = lane & 15, lg = lane >> 4;
    const int wm = wave >> 1, wn = wave & 1;
    const int n0 = blockIdx.x * 128, m0 = blockIdx.y * 128;

    const int srow = tid >> 2;
    const int scol = (tid & 3) * 8;
    const unsigned short* ga = A  + (size_t)(m0 + srow) * K + scol;
    const unsigned short* gb = Bt + (size_t)(n0 + srow) * K + scol;
    const int ldst = (tid & 0xC0) * 8;

    f32x4 acc[4][4];
#pragma unroll
    for (int i = 0; i < 4; i++)
#pragma unroll
        for (int j = 0; j < 4; j++) acc[i][j] = (f32x4){0.f, 0.f, 0.f, 0.f};

    for (int k0 = 0; k0 < K; k0 += 32) {
        __syncthreads();
#pragma unroll
        for (int i = 0; i < 2; i++) {
            __builtin_amdgcn_global_load_lds(
                (const __attribute__((address_space(1))) int*)(ga + k0 + (size_t)i * 64 * K),
                (__attribute__((address_space(3))) int*)&As[i * 2048 + ldst], 16, 0, 0);
            __builtin_amdgcn_global_load_lds(
                (const __attribute__((address_space(1))) int*)(gb + k0 + (size_t)i * 64 * K),
                (__attribute__((address_space(3))) int*)&Bs[i * 2048 + ldst], 16, 0, 0);
        }
        __syncthreads();

        bf16x8 af[4], bfr[4];
#pragma unroll
        for (int mi = 0; mi < 4; mi++)
            af[mi] = *(const bf16x8*)&As[(wm * 64 + mi * 16 + lr) * 32 + lg * 8];
#pragma unroll
        for (int ni = 0; ni < 4; ni++)
            bfr[ni] = *(const bf16x8*)&Bs[(wn * 64 + ni * 16 + lr) * 32 + lg * 8];
#pragma unroll
        for (int mi = 0; mi < 4; mi++)
#pragma unroll
            for (int ni = 0; ni < 4; ni++)
                acc[mi][ni] = __builtin_amdgcn_mfma_f32_16x16x32_bf16(
                    af[mi], bfr[ni], acc[mi][ni], 0, 0, 0);
    }

#pragma unroll
    for (int ni = 0; ni < 4; ni++) {
        const int col = n0 + wn * 64 + ni * 16 + lr;
        const float bv = bias[col];
        if (MODE == 0) {
#pragma unroll
            for (int mi = 0; mi < 4; mi++) {
#pragma unroll
                for (int r = 0; r < 4; r++) {
                    const int row = m0 + wm * 64 + mi * 16 + lg * 4 + r;
                    out[(size_t)row * N + col] = acc[mi][ni][r] + bv;
                }
            }
        } else {
            const int which = col >> 10;
            const int c  = col & 1023;
            const int hh = c >> 6;
            const int dd = c & 63;
            unsigned short* dst = (which == 0) ? qp : (which == 1) ? kp : vp;
#pragma unroll
            for (int mi = 0; mi < 4; mi++) {
#pragma unroll
                for (int r = 0; r < 4; r++) {
                    const int row = m0 + wm * 64 + mi * 16 + lg * 4 + r;
                    const int bb = row >> 11, tt = row & 2047;
                    dst[(((size_t)bb * H_ + hh) * T_ + tt) * D_ + dd] =
                        f2b(acc[mi][ni][r] + bv);
                }
            }
        }
    }
}

// ---------------------------------------------------------------------------
// chunk means
// ---------------------------------------------------------------------------
__global__ void chunk_mean_kernel(const float* __restrict__ x, float* __restrict__ cm)
{
    const int bc = blockIdx.x;
    const int b = bc >> 5, n = bc & 31;
    const float* xp = x + ((size_t)b * T_ + n * 64) * C_;
    for (int c = threadIdx.x; c < C_; c += blockDim.x) {
        float s = 0.f;
        for (int i = 0; i < 64; i++) s += xp[(size_t)i * C_ + c];
        cm[(size_t)bc * C_ + c] = s * (1.0f / 64.0f);
    }
}

// ---------------------------------------------------------------------------
// rowgemm32 / l2norm
// ---------------------------------------------------------------------------
__global__ void rowgemm32(const float* __restrict__ A, const float* __restrict__ W,
                          const float* __restrict__ bias, float* __restrict__ dst,
                          int M, int normalize)
{
    const int row  = blockIdx.x * 8 + (threadIdx.x >> 5);
    const int lane = threadIdx.x & 31;
    if (row >= M) return;
    const float* a = A + (size_t)row * C_;
    float acc = 0.f;
    for (int k = 0; k < C_; k += 4) {
        float4 a4 = *(const float4*)&a[k];
        acc += a4.x * W[(k + 0) * RD + lane];
        acc += a4.y * W[(k + 1) * RD + lane];
        acc += a4.z * W[(k + 2) * RD + lane];
        acc += a4.w * W[(k + 3) * RD + lane];
    }
    acc += bias[lane];
    if (normalize) {
        float ss = acc * acc;
#pragma unroll
        for (int off = 16; off >= 1; off >>= 1) ss += __shfl_xor(ss, off, 32);
        acc = acc / fmaxf(sqrtf(ss), 1e-12f);
    }
    dst[(size_t)row * RD + lane] = acc;
}

__global__ void l2norm_rows(const float* __restrict__ src, float* __restrict__ dst, int M)
{
    const int row  = blockIdx.x * 8 + (threadIdx.x >> 5);
    const int lane = threadIdx.x & 31;
    if (row >= M) return;
    float v = src[(size_t)row * RD + lane];
    float ss = v * v;
#pragma unroll
    for (int off = 16; off >= 1; off >>= 1) ss += __shfl_xor(ss, off, 32);
    dst[(size_t)row * RD + lane] = v / fmaxf(sqrtf(ss), 1e-12f);
}

// ---------------------------------------------------------------------------
// routing scores + top-8
// ---------------------------------------------------------------------------
__global__ void scores_topk(const float* __restrict__ qrt, const float* __restrict__ ren,
                            float* __restrict__ sc_out, float* __restrict__ idx_out)
{
    const int row = blockIdx.x * blockDim.x + threadIdx.x;
    if (row >= B_ * T_) return;
    const int b = row / T_;
    float q[RD];
#pragma unroll
    for (int i = 0; i < RD; i++) q[i] = qrt[(size_t)row * RD + i];
    const float* rb = ren + (size_t)b * NCH * RD;
    float s[NCH];
#pragma unroll 4
    for (int n = 0; n < NCH; n++) {
        float acc = 0.f;
#pragma unroll
        for (int i = 0; i < RD; i++) acc += q[i] * rb[n * RD + i];
        s[n] = acc;
        sc_out[(size_t)row * NCH + n] = acc;
    }
    unsigned mask = 0;
    for (int t = 0; t < TOPB; t++) {
        float best = -INFINITY;
        int bi = 0;
#pragma unroll
        for (int n = 0; n < NCH; n++) {
            const bool ok = !((mask >> n) & 1u) && (s[n] > best);
            if (ok) { best = s[n]; bi = n; }
        }
        mask |= (1u << bi);
        idx_out[(size_t)row * TOPB + t] = (float)bi;
    }
}

// ---------------------------------------------------------------------------
// MFMA bf16 flash attention, v3: paired q-tiles for perfect balance.
//  - 512 blocks; block = (b, h, pair{qtA=31-pi, qtB=pi}) -> exactly 33
//    S-tiles of compute per block; K/V staged once for both q-tiles.
//  - XCD pinning: bid&7 -> h in {x, x+8} (K/V L2-resident per XCD)
//  - defer-max (THR=8) skips oacc rescale on stable-max tiles
//  - exp2-domain softmax: 1/ln2 folded into the QK scale
// ---------------------------------------------------------------------------
#define LSTR 78
#define SCALE2 0.18033688f   /* 0.125 * 1.44269504 */

#define FLASH_TILE(S, M, L, O, ROW0, DIAG)                                    \
  do {                                                                        \
    if (DIAG) {                                                               \
      _Pragma("unroll")                                                       \
      for (int cb = 0; cb < 4; cb++) {                                        \
        const int col_g = kt * 64 + cb * 16 + lr;                             \
        _Pragma("unroll")                                                     \
        for (int r = 0; r < 4; r++) {                                         \
          float sv = S[cb][r] * SCALE2;                                       \
          if (col_g > (ROW0) + r) sv = -INFINITY;                             \
          S[cb][r] = sv;                                                      \
        }                                                                     \
      }                                                                       \
    } else {                                                                  \
      _Pragma("unroll")                                                       \
      for (int cb = 0; cb < 4; cb++)                                          \
        _Pragma("unroll")                                                     \
        for (int r = 0; r < 4; r++) S[cb][r] *= SCALE2;                       \
    }                                                                         \
    float rm[4];                                                              \
    _Pragma("unroll")                                                         \
    for (int r = 0; r < 4; r++)                                               \
      rm[r] = fmaxf(fmaxf(S[0][r], S[1][r]), fmaxf(S[2][r], S[3][r]));        \
    _Pragma("unroll")                                                         \
    for (int off = 1; off <= 8; off <<= 1)                                    \
      _Pragma("unroll")                                                       \
      for (int r = 0; r < 4; r++) rm[r] = fmaxf(rm[r], __shfl_xor(rm[r], off)); \
    bool keep = true;                                                         \
    _Pragma("unroll")                                                         \
    for (int r = 0; r < 4; r++) keep = keep && (rm[r] <= M[r] + 8.0f);        \
    if (!__all(keep)) {                                                       \
      _Pragma("unroll")                                                       \
      for (int r = 0; r < 4; r++) {                                           \
        const float mnew = fmaxf(M[r], rm[r]);                                \
        const float fsc  = exp2f(M[r] - mnew);                                \
        M[r] = mnew;                                                          \
        L[r] *= fsc;                                                          \
        _Pragma("unroll")                                                     \
        for (int db = 0; db < 4; db++) O[db][r] *= fsc;                       \
      }                                                                       \
    }                                                                         \
    float rs[4] = {0.f, 0.f, 0.f, 0.f};                                       \
    _Pragma("unroll")                                                         \
    for (int cb = 0; cb < 4; cb++) {                                          \
      _Pragma("unroll")                                                       \
      for (int r = 0; r < 4; r++) {                                           \
        const float p = exp2f(S[cb][r] - M[r]);                               \
        rs[r] += p;                                                           \
        Ps[wave][lg * 4 + r][cb * 16 + lr] = (short)f2b(p);                   \
      }                                                                       \
    }                                                                         \
    _Pragma("unroll")                                                         \
    for (int off = 1; off <= 8; off <<= 1)                                    \
      _Pragma("unroll")                                                       \
      for (int r = 0; r < 4; r++) rs[r] += __shfl_xor(rs[r], off);            \
    _Pragma("unroll")                                                         \
    for (int r = 0; r < 4; r++) L[r] += rs[r];                                \
    bf16x8 pf0 = *(const bf16x8*)&Ps[wave][lr][lg * 8];                       \
    bf16x8 pf1 = *(const bf16x8*)&Ps[wave][lr][32 + lg * 8];                  \
    _Pragma("unroll")                                                         \
    for (int db = 0; db < 4; db++) {                                          \
      bf16x8 vf0 = *(const bf16x8*)&Vt[db * 16 + lr][lg * 8];                 \
      bf16x8 vf1 = *(const bf16x8*)&Vt[db * 16 + lr][32 + lg * 8];            \
      O[db] = __builtin_amdgcn_mfma_f32_16x16x32_bf16(pf0, vf0, O[db], 0, 0, 0); \
      O[db] = __builtin_amdgcn_mfma_f32_16x16x32_bf16(pf1, vf1, O[db], 0, 0, 0); \
    }                                                                         \
  } while (0)

__global__ __launch_bounds__(256) void attn_mfma(
    const unsigned short* __restrict__ qg, const unsigned short* __restrict__ kg,
    const unsigned short* __restrict__ vg, unsigned short* __restrict__ y)
{
    // 512 blocks -> (b, h, qt-pair); same-h pinned to one XCD
    const int bid = blockIdx.x;
    const int xcd = bid & 7;
    const int j   = bid >> 3;                 // 0..63
    const int h   = xcd + 8 * (j & 1);
    const int b   = (j >> 1) & 1;
    const int pi  = j >> 2;                   // 0..15
    const int qtA = 31 - pi;                  // long tile
    const int qtB = pi;                       // short tile

    const int tid  = threadIdx.x;
    const int wave = tid >> 6;
    const int lane = tid & 63;
    const int lg = lane >> 4;
    const int lr = lane & 15;

    __shared__ short Ks[64][LSTR];
    __shared__ short Vt[64][LSTR];
    __shared__ short Ps[4][16][LSTR];

    const size_t base = ((size_t)(b * H_ + h) * T_) * D_;

    // Q fragments for both tiles
    bf16x8 qfA0, qfA1, qfB0, qfB1;
    {
        const short* qpA = (const short*)qg + base + (size_t)(qtA * 64 + wave * 16 + lr) * D_;
        qfA0 = *(const bf16x8*)&qpA[lg * 8];
        qfA1 = *(const bf16x8*)&qpA[32 + lg * 8];
        const short* qpB = (const short*)qg + base + (size_t)(qtB * 64 + wave * 16 + lr) * D_;
        qfB0 = *(const bf16x8*)&qpB[lg * 8];
        qfB1 = *(const bf16x8*)&qpB[32 + lg * 8];
    }

    // staging indices
    const int srr = tid >> 2;            // K row 0..63
    const int sc0 = (tid & 3) * 16;      // K col base
    const int vrp = tid >> 3;            // V row-pair 0..31
    const int vcg = tid & 7;             // V col-group 0..7

    bf16x8 kreg0, kreg1, vreg0, vreg1;

    float mA[4], lA[4], mB[4], lB[4];
    f32x4 oA[4], oB[4];
#pragma unroll
    for (int r = 0; r < 4; r++) {
        mA[r] = -INFINITY; lA[r] = 0.f;
        mB[r] = -INFINITY; lB[r] = 0.f;
        oA[r] = (f32x4){0.f, 0.f, 0.f, 0.f};
        oB[r] = (f32x4){0.f, 0.f, 0.f, 0.f};
    }

    const int rowA0 = qtA * 64 + wave * 16 + lg * 4;
    const int rowB0 = qtB * 64 + wave * 16 + lg * 4;

    // prologue loads for tile 0
    {
        const short* kp = (const short*)kg + base + (size_t)srr * D_ + sc0;
        kreg0 = *(const bf16x8*)kp;
        kreg1 = *(const bf16x8*)(kp + 8);
        const short* vp = (const short*)vg + base + (size_t)(2 * vrp) * D_ + vcg * 8;
        vreg0 = *(const bf16x8*)vp;
        vreg1 = *(const bf16x8*)(vp + D_);
    }

    for (int kt = 0; kt <= qtA; ++kt) {
        __syncthreads();
        *(bf16x8*)&Ks[srr][sc0]     = kreg0;
        *(bf16x8*)&Ks[srr][sc0 + 8] = kreg1;
#pragma unroll
        for (int jj = 0; jj < 8; jj++) {
            const unsigned int dw = ((unsigned int)(unsigned short)vreg0[jj]) |
                                    (((unsigned int)(unsigned short)vreg1[jj]) << 16);
            *(unsigned int*)&Vt[vcg * 8 + jj][2 * vrp] = dw;
        }
        __syncthreads();

        if (kt < qtA) {
            const short* kp = (const short*)kg + base + (size_t)((kt + 1) * 64 + srr) * D_ + sc0;
            kreg0 = *(const bf16x8*)kp;
            kreg1 = *(const bf16x8*)(kp + 8);
            const short* vp = (const short*)vg + base + (size_t)((kt + 1) * 64 + 2 * vrp) * D_ + vcg * 8;
            vreg0 = *(const bf16x8*)vp;
            vreg1 = *(const bf16x8*)(vp + D_);
        }

        const bool doB = (kt <= qtB);

        // QK^T for both q-tiles sharing the K-fragment reads
        f32x4 sA[4], sB[4];
#pragma unroll
        for (int cb = 0; cb < 4; cb++) {
            bf16x8 kf0 = *(const bf16x8*)&Ks[cb * 16 + lr][lg * 8];
            bf16x8 kf1 = *(const bf16x8*)&Ks[cb * 16 + lr][32 + lg * 8];
            f32x4 acc = (f32x4){0.f, 0.f, 0.f, 0.f};
            acc = __builtin_amdgcn_mfma_f32_16x16x32_bf16(qfA0, kf0, acc, 0, 0, 0);
            acc = __builtin_amdgcn_mfma_f32_16x16x32_bf16(qfA1, kf1, acc, 0, 0, 0);
            sA[cb] = acc;
            if (doB) {
                f32x4 acc2 = (f32x4){0.f, 0.f, 0.f, 0.f};
                acc2 = __builtin_amdgcn_mfma_f32_16x16x32_bf16(qfB0, kf0, acc2, 0, 0, 0);
                acc2 = __builtin_amdgcn_mfma_f32_16x16x32_bf16(qfB1, kf1, acc2, 0, 0, 0);
                sB[cb] = acc2;
            }
        }

        FLASH_TILE(sA, mA, lA, oA, rowA0, kt == qtA);
        if (doB) {
            FLASH_TILE(sB, mB, lB, oB, rowB0, kt == qtB);
        }
    }

    // epilogues
#pragma unroll
    for (int r = 0; r < 4; r++) {
        const float invA = 1.0f / lA[r];
        const int trA = qtA * 64 + wave * 16 + lg * 4 + r;
        unsigned short* ypA = y + (size_t)(b * T_ + trA) * C_ + h * D_;
#pragma unroll
        for (int db = 0; db < 4; db++)
            ypA[db * 16 + lr] = f2b(oA[db][r] * invA);

        const float invB = 1.0f / lB[r];
        const int trB = qtB * 64 + wave * 16 + lg * 4 + r;
        unsigned short* ypB = y + (size_t)(b * T_ + trB) * C_ + h * D_;
#pragma unroll
        for (int db = 0; db < 4; db++)
            ypB[db * 16 + lr] = f2b(oB[db][r] * invB);
    }
}

// ---------------------------------------------------------------------------
extern "C" void kernel_launch(void* const* d_in, const int* in_sizes, int n_in,
                              void* d_out, int out_size, void* d_ws, size_t ws_size,
                              hipStream_t stream)
{
    const float* x       = (const float*)d_in[0];
    const float* Wqkv    = (const float*)d_in[1];
    const float* bqkv    = (const float*)d_in[2];
    const float* Wproj   = (const float*)d_in[3];
    const float* bproj   = (const float*)d_in[4];
    const float* Wrouter = (const float*)d_in[5];
    const float* brouter = (const float*)d_in[6];
    const float* Wq_rt   = (const float*)d_in[7];
    const float* bq_rt   = (const float*)d_in[8];

    float* out = (float*)d_out;
    char*  ws  = (char*)d_ws;

    const size_t MT  = (size_t)B_ * T_;
    const size_t QKV = MT * C_;

    unsigned short* xb   = (unsigned short*)ws;
    unsigned short* Wqt  = xb  + QKV;
    unsigned short* Wpt  = Wqt + (size_t)3 * C_ * C_;
    unsigned short* q    = Wpt + (size_t)C_ * C_;
    unsigned short* k    = q + QKV;
    unsigned short* v    = k + QKV;
    unsigned short* yab  = v + QKV;
    float* cm  = (float*)(yab + QKV);
    float* qrt = cm  + (size_t)B_ * NCH * C_;
    float* ren = qrt + MT * RD;

    float* y_out   = out;
    float* idx_out = out + QKV;
    float* sc_out  = idx_out + MT * TOPB;
    float* emb_out = sc_out + MT * NCH;

    // 0) casts / transposes
    cast_bf16_kernel<<<(int)(QKV / 8 / 256), 256, 0, stream>>>(x, xb, (int)(QKV / 8));
    transpose_cast_kernel<<<dim3(3 * C_ / 64, C_ / 64), 256, 0, stream>>>(Wqkv, Wqt, C_, 3 * C_);
    transpose_cast_kernel<<<dim3(C_ / 64, C_ / 64), 256, 0, stream>>>(Wproj, Wpt, C_, C_);

    // 1) qkv projection (MFMA) -> bf16 q,k,v [B,H,T,D]
    gemm_mfma<1><<<dim3(3 * C_ / 128, MT / 128), 256, 0, stream>>>(
        xb, Wqt, bqkv, nullptr, q, k, v, (int)MT, 3 * C_, C_);

    // 2) routing path (fp32)
    chunk_mean_kernel<<<B_ * NCH, 256, 0, stream>>>(x, cm);
    rowgemm32<<<(B_ * NCH + 7) / 8, 256, 0, stream>>>(cm, Wrouter, brouter, emb_out, B_ * NCH, 0);
    l2norm_rows<<<(B_ * NCH + 7) / 8, 256, 0, stream>>>(emb_out, ren, B_ * NCH);
    rowgemm32<<<((int)MT + 7) / 8, 256, 0, stream>>>(x, Wq_rt, bq_rt, qrt, (int)MT, 1);
    scores_topk<<<((int)MT + 255) / 256, 256, 0, stream>>>(qrt, ren, sc_out, idx_out);

    // 3) MFMA flash attention (paired q-tiles) -> bf16 ya [B,T,C]
    attn_mfma<<<dim3(512), 256, 0, stream>>>(q, k, v, yab);

    // 4) output projection (MFMA) -> f32 y
    gemm_mfma<0><<<dim3(C_ / 128, MT / 128), 256, 0, stream>>>(
        yab, Wpt, bproj, y_out, nullptr, nullptr, nullptr, (int)MT, C_, C_);
}

// Round 6
// 257.505 us; speedup vs baseline: 1.0530x; 1.0530x over previous
//
#include <hip/hip_runtime.h>
#include <hip/hip_bf16.h>
#include <math.h>

#define B_   2
#define T_   2048
#define C_   1024
#define H_   16
#define D_   64
#define NCH  32
#define RD   32
#define TOPB 8

typedef __attribute__((ext_vector_type(8))) short bf16x8;
typedef __attribute__((ext_vector_type(4))) float f32x4;

static __device__ __forceinline__ unsigned short f2b(float f) {
    return __bfloat16_as_ushort(__float2bfloat16(f));
}

// ---------------------------------------------------------------------------
// cast x (f32) -> bf16, 8 elements per thread
// ---------------------------------------------------------------------------
__global__ __launch_bounds__(256) void cast_bf16_kernel(
    const float* __restrict__ in, unsigned short* __restrict__ out, int n8)
{
    const int i = blockIdx.x * blockDim.x + threadIdx.x;
    if (i >= n8) return;
    float4 a = ((const float4*)in)[i * 2];
    float4 b = ((const float4*)in)[i * 2 + 1];
    bf16x8 o;
    o[0] = (short)f2b(a.x); o[1] = (short)f2b(a.y);
    o[2] = (short)f2b(a.z); o[3] = (short)f2b(a.w);
    o[4] = (short)f2b(b.x); o[5] = (short)f2b(b.y);
    o[6] = (short)f2b(b.z); o[7] = (short)f2b(b.w);
    *(bf16x8*)&out[i * 8] = o;
}

// ---------------------------------------------------------------------------
// W [K][N] f32 -> Wt [N][K] bf16, 64x64 tiles via LDS
// ---------------------------------------------------------------------------
__global__ __launch_bounds__(256) void transpose_cast_kernel(
    const float* __restrict__ W, unsigned short* __restrict__ Wt, int K, int N)
{
    __shared__ float t[64][65];
    const int tid = threadIdx.x;
    const int n0 = blockIdx.x * 64, k0 = blockIdx.y * 64;
#pragma unroll
    for (int i = 0; i < 4; i++) {
        const int f = tid + i * 256;
        const int r = f >> 4, c4 = (f & 15) * 4;
        float4 v = *(const float4*)&W[(size_t)(k0 + r) * N + n0 + c4];
        t[r][c4 + 0] = v.x; t[r][c4 + 1] = v.y;
        t[r][c4 + 2] = v.z; t[r][c4 + 3] = v.w;
    }
    __syncthreads();
#pragma unroll
    for (int i = 0; i < 2; i++) {
        const int s = tid + i * 256;
        const int rn = s >> 3, ck8 = (s & 7) * 8;
        bf16x8 o;
#pragma unroll
        for (int j = 0; j < 8; j++) o[j] = (short)f2b(t[ck8 + j][rn]);
        *(bf16x8*)&Wt[(size_t)(n0 + rn) * K + k0 + ck8] = o;
    }
}

// ---------------------------------------------------------------------------
// bf16 MFMA GEMM (m97 structure): C = A[M,K] @ Bt[N,K]^T + bias
// ---------------------------------------------------------------------------
template <int MODE>
__global__ __launch_bounds__(256) void gemm_mfma(
    const unsigned short* __restrict__ A, const unsigned short* __restrict__ Bt,
    const float* __restrict__ bias, float* __restrict__ out,
    unsigned short* __restrict__ qp, unsigned short* __restrict__ kp,
    unsigned short* __restrict__ vp, int M, int N, int K)
{
    __shared__ unsigned short As[128 * 32];
    __shared__ unsigned short Bs[128 * 32];

    const int tid  = threadIdx.x;
    const int lane = tid & 63;
    const int wave = tid >> 6;
    const int lr = lane & 15, lg = lane >> 4;
    const int wm = wave >> 1, wn = wave & 1;
    const int n0 = blockIdx.x * 128, m0 = blockIdx.y * 128;

    const int srow = tid >> 2;
    const int scol = (tid & 3) * 8;
    const unsigned short* ga = A  + (size_t)(m0 + srow) * K + scol;
    const unsigned short* gb = Bt + (size_t)(n0 + srow) * K + scol;
    const int ldst = (tid & 0xC0) * 8;

    f32x4 acc[4][4];
#pragma unroll
    for (int i = 0; i < 4; i++)
#pragma unroll
        for (int j = 0; j < 4; j++) acc[i][j] = (f32x4){0.f, 0.f, 0.f, 0.f};

    for (int k0 = 0; k0 < K; k0 += 32) {
        __syncthreads();
#pragma unroll
        for (int i = 0; i < 2; i++) {
            __builtin_amdgcn_global_load_lds(
                (const __attribute__((address_space(1))) int*)(ga + k0 + (size_t)i * 64 * K),
                (__attribute__((address_space(3))) int*)&As[i * 2048 + ldst], 16, 0, 0);
            __builtin_amdgcn_global_load_lds(
                (const __attribute__((address_space(1))) int*)(gb + k0 + (size_t)i * 64 * K),
                (__attribute__((address_space(3))) int*)&Bs[i * 2048 + ldst], 16, 0, 0);
        }
        __syncthreads();

        bf16x8 af[4], bfr[4];
#pragma unroll
        for (int mi = 0; mi < 4; mi++)
            af[mi] = *(const bf16x8*)&As[(wm * 64 + mi * 16 + lr) * 32 + lg * 8];
#pragma unroll
        for (int ni = 0; ni < 4; ni++)
            bfr[ni] = *(const bf16x8*)&Bs[(wn * 64 + ni * 16 + lr) * 32 + lg * 8];
#pragma unroll
        for (int mi = 0; mi < 4; mi++)
#pragma unroll
            for (int ni = 0; ni < 4; ni++)
                acc[mi][ni] = __builtin_amdgcn_mfma_f32_16x16x32_bf16(
                    af[mi], bfr[ni], acc[mi][ni], 0, 0, 0);
    }

#pragma unroll
    for (int ni = 0; ni < 4; ni++) {
        const int col = n0 + wn * 64 + ni * 16 + lr;
        const float bv = bias[col];
        if (MODE == 0) {
#pragma unroll
            for (int mi = 0; mi < 4; mi++) {
#pragma unroll
                for (int r = 0; r < 4; r++) {
                    const int row = m0 + wm * 64 + mi * 16 + lg * 4 + r;
                    out[(size_t)row * N + col] = acc[mi][ni][r] + bv;
                }
            }
        } else {
            const int which = col >> 10;
            const int c  = col & 1023;
            const int hh = c >> 6;
            const int dd = c & 63;
            unsigned short* dst = (which == 0) ? qp : (which == 1) ? kp : vp;
#pragma unroll
            for (int mi = 0; mi < 4; mi++) {
#pragma unroll
                for (int r = 0; r < 4; r++) {
                    const int row = m0 + wm * 64 + mi * 16 + lg * 4 + r;
                    const int bb = row >> 11, tt = row & 2047;
                    dst[(((size_t)bb * H_ + hh) * T_ + tt) * D_ + dd] =
                        f2b(acc[mi][ni][r] + bv);
                }
            }
        }
    }
}

// ---------------------------------------------------------------------------
// chunk means
// ---------------------------------------------------------------------------
__global__ void chunk_mean_kernel(const float* __restrict__ x, float* __restrict__ cm)
{
    const int bc = blockIdx.x;
    const int b = bc >> 5, n = bc & 31;
    const float* xp = x + ((size_t)b * T_ + n * 64) * C_;
    for (int c = threadIdx.x; c < C_; c += blockDim.x) {
        float s = 0.f;
        for (int i = 0; i < 64; i++) s += xp[(size_t)i * C_ + c];
        cm[(size_t)bc * C_ + c] = s * (1.0f / 64.0f);
    }
}

// ---------------------------------------------------------------------------
// rowgemm32 / l2norm
// ---------------------------------------------------------------------------
__global__ void rowgemm32(const float* __restrict__ A, const float* __restrict__ W,
                          const float* __restrict__ bias, float* __restrict__ dst,
                          int M, int normalize)
{
    const int row  = blockIdx.x * 8 + (threadIdx.x >> 5);
    const int lane = threadIdx.x & 31;
    if (row >= M) return;
    const float* a = A + (size_t)row * C_;
    float acc = 0.f;
    for (int k = 0; k < C_; k += 4) {
        float4 a4 = *(const float4*)&a[k];
        acc += a4.x * W[(k + 0) * RD + lane];
        acc += a4.y * W[(k + 1) * RD + lane];
        acc += a4.z * W[(k + 2) * RD + lane];
        acc += a4.w * W[(k + 3) * RD + lane];
    }
    acc += bias[lane];
    if (normalize) {
        float ss = acc * acc;
#pragma unroll
        for (int off = 16; off >= 1; off >>= 1) ss += __shfl_xor(ss, off, 32);
        acc = acc / fmaxf(sqrtf(ss), 1e-12f);
    }
    dst[(size_t)row * RD + lane] = acc;
}

__global__ void l2norm_rows(const float* __restrict__ src, float* __restrict__ dst, int M)
{
    const int row  = blockIdx.x * 8 + (threadIdx.x >> 5);
    const int lane = threadIdx.x & 31;
    if (row >= M) return;
    float v = src[(size_t)row * RD + lane];
    float ss = v * v;
#pragma unroll
    for (int off = 16; off >= 1; off >>= 1) ss += __shfl_xor(ss, off, 32);
    dst[(size_t)row * RD + lane] = v / fmaxf(sqrtf(ss), 1e-12f);
}

// ---------------------------------------------------------------------------
// routing scores + top-8
// ---------------------------------------------------------------------------
__global__ void scores_topk(const float* __restrict__ qrt, const float* __restrict__ ren,
                            float* __restrict__ sc_out, float* __restrict__ idx_out)
{
    const int row = blockIdx.x * blockDim.x + threadIdx.x;
    if (row >= B_ * T_) return;
    const int b = row / T_;
    float q[RD];
#pragma unroll
    for (int i = 0; i < RD; i++) q[i] = qrt[(size_t)row * RD + i];
    const float* rb = ren + (size_t)b * NCH * RD;
    float s[NCH];
#pragma unroll 4
    for (int n = 0; n < NCH; n++) {
        float acc = 0.f;
#pragma unroll
        for (int i = 0; i < RD; i++) acc += q[i] * rb[n * RD + i];
        s[n] = acc;
        sc_out[(size_t)row * NCH + n] = acc;
    }
    unsigned mask = 0;
    for (int t = 0; t < TOPB; t++) {
        float best = -INFINITY;
        int bi = 0;
#pragma unroll
        for (int n = 0; n < NCH; n++) {
            const bool ok = !((mask >> n) & 1u) && (s[n] > best);
            if (ok) { best = s[n]; bi = n; }
        }
        mask |= (1u << bi);
        idx_out[(size_t)row * TOPB + t] = (float)bi;
    }
}

// ---------------------------------------------------------------------------
// MFMA bf16 flash attention, v4.
//  - 1024 blocks (b,h,qt), qt-descending, XCD-pinned (h in {x,x+8} per XCD)
//  - LDS stride 68 shorts: Ps writes & V^T staging land 2 lanes/bank (free)
//  - K/V LDS double-buffered -> ONE barrier per K-tile
//  - reg-staged K/V with next-tile loads issued a full iteration early (T14)
//  - defer-max (THR=8, log2 domain) + exp2 softmax
// ---------------------------------------------------------------------------
#define LSTR 68
#define SCALE2 0.18033688f   /* 0.125 * 1.44269504 */

__global__ __launch_bounds__(256) void attn_mfma(
    const unsigned short* __restrict__ qg, const unsigned short* __restrict__ kg,
    const unsigned short* __restrict__ vg, unsigned short* __restrict__ y)
{
    const int bid = blockIdx.x;
    const int xcd = bid & 7;
    const int j   = bid >> 3;                 // 0..127
    const int h   = xcd + 8 * (j & 1);
    const int b   = (j >> 1) & 1;
    const int qt  = 31 - (j >> 2);            // long blocks dispatch first

    const int tid  = threadIdx.x;
    const int wave = tid >> 6;
    const int lane = tid & 63;
    const int lg = lane >> 4;
    const int lr = lane & 15;

    __shared__ short Ks[2][64][LSTR];
    __shared__ short Vt[2][64][LSTR];     // Vt[buf][d][kv]
    __shared__ short Ps[4][16][LSTR];

    const size_t base = ((size_t)(b * H_ + h) * T_) * D_;

    // Q fragments, hoisted
    bf16x8 qf0, qf1;
    {
        const short* qp = (const short*)qg + base + (size_t)(qt * 64 + wave * 16 + lr) * D_;
        qf0 = *(const bf16x8*)&qp[lg * 8];
        qf1 = *(const bf16x8*)&qp[32 + lg * 8];
    }

    // staging indices
    const int srr = tid >> 2;            // K row 0..63
    const int sc0 = (tid & 3) * 16;      // K col base
    const int vrp = tid & 31;            // V row-pair 0..31 (bank-partitioned writes)
    const int vcg = tid >> 5;            // V col-group 0..7

    bf16x8 kreg0, kreg1, vreg0, vreg1;

    float m_run[4], l_run[4];
    f32x4 oacc[4];
#pragma unroll
    for (int r = 0; r < 4; r++) {
        m_run[r] = -INFINITY;
        l_run[r] = 0.f;
        oacc[r] = (f32x4){0.f, 0.f, 0.f, 0.f};
    }
    const int row0 = qt * 64 + wave * 16 + lg * 4;

    // prologue: load tile 0, stage to buf0; prefetch tile 1
    {
        const short* kp = (const short*)kg + base + (size_t)srr * D_ + sc0;
        kreg0 = *(const bf16x8*)kp;
        kreg1 = *(const bf16x8*)(kp + 8);
        const short* vp = (const short*)vg + base + (size_t)(2 * vrp) * D_ + vcg * 8;
        vreg0 = *(const bf16x8*)vp;
        vreg1 = *(const bf16x8*)(vp + D_);
    }
    {
        *(bf16x8*)&Ks[0][srr][sc0]     = kreg0;
        *(bf16x8*)&Ks[0][srr][sc0 + 8] = kreg1;
#pragma unroll
        for (int jj = 0; jj < 8; jj++) {
            const unsigned int dw = ((unsigned int)(unsigned short)vreg0[jj]) |
                                    (((unsigned int)(unsigned short)vreg1[jj]) << 16);
            *(unsigned int*)&Vt[0][vcg * 8 + jj][2 * vrp] = dw;
        }
    }
    if (qt >= 1) {
        const short* kp = (const short*)kg + base + (size_t)(64 + srr) * D_ + sc0;
        kreg0 = *(const bf16x8*)kp;
        kreg1 = *(const bf16x8*)(kp + 8);
        const short* vp = (const short*)vg + base + (size_t)(64 + 2 * vrp) * D_ + vcg * 8;
        vreg0 = *(const bf16x8*)vp;
        vreg1 = *(const bf16x8*)(vp + D_);
    }
    __syncthreads();

    for (int kt = 0; kt <= qt; ++kt) {
        const int cur = kt & 1;

        // stage kt+1's regs into the other buffer (its readers finished last iter)
        if (kt < qt) {
            *(bf16x8*)&Ks[cur ^ 1][srr][sc0]     = kreg0;
            *(bf16x8*)&Ks[cur ^ 1][srr][sc0 + 8] = kreg1;
#pragma unroll
            for (int jj = 0; jj < 8; jj++) {
                const unsigned int dw = ((unsigned int)(unsigned short)vreg0[jj]) |
                                        (((unsigned int)(unsigned short)vreg1[jj]) << 16);
                *(unsigned int*)&Vt[cur ^ 1][vcg * 8 + jj][2 * vrp] = dw;
            }
        }
        // issue kt+2's global loads (a full iteration of latency slack)
        if (kt + 2 <= qt) {
            const short* kp = (const short*)kg + base + (size_t)((kt + 2) * 64 + srr) * D_ + sc0;
            kreg0 = *(const bf16x8*)kp;
            kreg1 = *(const bf16x8*)(kp + 8);
            const short* vp = (const short*)vg + base + (size_t)((kt + 2) * 64 + 2 * vrp) * D_ + vcg * 8;
            vreg0 = *(const bf16x8*)vp;
            vreg1 = *(const bf16x8*)(vp + D_);
        }

        // QK^T from buf[cur]
        f32x4 s[4];
#pragma unroll
        for (int cb = 0; cb < 4; cb++) {
            bf16x8 kf0 = *(const bf16x8*)&Ks[cur][cb * 16 + lr][lg * 8];
            bf16x8 kf1 = *(const bf16x8*)&Ks[cur][cb * 16 + lr][32 + lg * 8];
            f32x4 acc = (f32x4){0.f, 0.f, 0.f, 0.f};
            acc = __builtin_amdgcn_mfma_f32_16x16x32_bf16(qf0, kf0, acc, 0, 0, 0);
            acc = __builtin_amdgcn_mfma_f32_16x16x32_bf16(qf1, kf1, acc, 0, 0, 0);
            s[cb] = acc;
        }

        // scale (log2 domain) + causal mask on diagonal tile
        if (kt == qt) {
#pragma unroll
            for (int cb = 0; cb < 4; cb++) {
                const int col_g = kt * 64 + cb * 16 + lr;
#pragma unroll
                for (int r = 0; r < 4; r++) {
                    float sv = s[cb][r] * SCALE2;
                    if (col_g > row0 + r) sv = -INFINITY;
                    s[cb][r] = sv;
                }
            }
        } else {
#pragma unroll
            for (int cb = 0; cb < 4; cb++)
#pragma unroll
                for (int r = 0; r < 4; r++) s[cb][r] *= SCALE2;
        }

        // row max
        float rm[4];
#pragma unroll
        for (int r = 0; r < 4; r++)
            rm[r] = fmaxf(fmaxf(s[0][r], s[1][r]), fmaxf(s[2][r], s[3][r]));
#pragma unroll
        for (int off = 1; off <= 8; off <<= 1)
#pragma unroll
            for (int r = 0; r < 4; r++) rm[r] = fmaxf(rm[r], __shfl_xor(rm[r], off));

        // defer-max: only rescale when max grew past threshold (log2 dom, THR=8)
        bool keep = true;
#pragma unroll
        for (int r = 0; r < 4; r++) keep = keep && (rm[r] <= m_run[r] + 8.0f);
        if (!__all(keep)) {
#pragma unroll
            for (int r = 0; r < 4; r++) {
                const float mnew = fmaxf(m_run[r], rm[r]);
                const float fsc  = exp2f(m_run[r] - mnew);
                m_run[r] = mnew;
                l_run[r] *= fsc;
#pragma unroll
                for (int db = 0; db < 4; db++) oacc[db][r] *= fsc;
            }
        }

        // P = exp2(S - m) -> bf16 wave-private LDS; row sums
        float rs[4] = {0.f, 0.f, 0.f, 0.f};
#pragma unroll
        for (int cb = 0; cb < 4; cb++) {
#pragma unroll
            for (int r = 0; r < 4; r++) {
                const float p = exp2f(s[cb][r] - m_run[r]);
                rs[r] += p;
                Ps[wave][lg * 4 + r][cb * 16 + lr] = (short)f2b(p);
            }
        }
#pragma unroll
        for (int off = 1; off <= 8; off <<= 1)
#pragma unroll
            for (int r = 0; r < 4; r++) rs[r] += __shfl_xor(rs[r], off);
#pragma unroll
        for (int r = 0; r < 4; r++) l_run[r] += rs[r];

        // PV from buf[cur]
        bf16x8 pf0 = *(const bf16x8*)&Ps[wave][lr][lg * 8];
        bf16x8 pf1 = *(const bf16x8*)&Ps[wave][lr][32 + lg * 8];
#pragma unroll
        for (int db = 0; db < 4; db++) {
            bf16x8 vf0 = *(const bf16x8*)&Vt[cur][db * 16 + lr][lg * 8];
            bf16x8 vf1 = *(const bf16x8*)&Vt[cur][db * 16 + lr][32 + lg * 8];
            oacc[db] = __builtin_amdgcn_mfma_f32_16x16x32_bf16(pf0, vf0, oacc[db], 0, 0, 0);
            oacc[db] = __builtin_amdgcn_mfma_f32_16x16x32_bf16(pf1, vf1, oacc[db], 0, 0, 0);
        }

        __syncthreads();   // buf[cur^1] writes done; buf[cur] readers done
    }

    // epilogue
#pragma unroll
    for (int r = 0; r < 4; r++) {
        const float inv = 1.0f / l_run[r];
        const int trow = qt * 64 + wave * 16 + lg * 4 + r;
        unsigned short* yp = y + (size_t)(b * T_ + trow) * C_ + h * D_;
#pragma unroll
        for (int db = 0; db < 4; db++)
            yp[db * 16 + lr] = f2b(oacc[db][r] * inv);
    }
}

// ---------------------------------------------------------------------------
extern "C" void kernel_launch(void* const* d_in, const int* in_sizes, int n_in,
                              void* d_out, int out_size, void* d_ws, size_t ws_size,
                              hipStream_t stream)
{
    const float* x       = (const float*)d_in[0];
    const float* Wqkv    = (const float*)d_in[1];
    const float* bqkv    = (const float*)d_in[2];
    const float* Wproj   = (const float*)d_in[3];
    const float* bproj   = (const float*)d_in[4];
    const float* Wrouter = (const float*)d_in[5];
    const float* brouter = (const float*)d_in[6];
    const float* Wq_rt   = (const float*)d_in[7];
    const float* bq_rt   = (const float*)d_in[8];

    float* out = (float*)d_out;
    char*  ws  = (char*)d_ws;

    const size_t MT  = (size_t)B_ * T_;
    const size_t QKV = MT * C_;

    unsigned short* xb   = (unsigned short*)ws;
    unsigned short* Wqt  = xb  + QKV;
    unsigned short* Wpt  = Wqt + (size_t)3 * C_ * C_;
    unsigned short* q    = Wpt + (size_t)C_ * C_;
    unsigned short* k    = q + QKV;
    unsigned short* v    = k + QKV;
    unsigned short* yab  = v + QKV;
    float* cm  = (float*)(yab + QKV);
    float* qrt = cm  + (size_t)B_ * NCH * C_;
    float* ren = qrt + MT * RD;

    float* y_out   = out;
    float* idx_out = out + QKV;
    float* sc_out  = idx_out + MT * TOPB;
    float* emb_out = sc_out + MT * NCH;

    // 0) casts / transposes
    cast_bf16_kernel<<<(int)(QKV / 8 / 256), 256, 0, stream>>>(x, xb, (int)(QKV / 8));
    transpose_cast_kernel<<<dim3(3 * C_ / 64, C_ / 64), 256, 0, stream>>>(Wqkv, Wqt, C_, 3 * C_);
    transpose_cast_kernel<<<dim3(C_ / 64, C_ / 64), 256, 0, stream>>>(Wproj, Wpt, C_, C_);

    // 1) qkv projection (MFMA) -> bf16 q,k,v [B,H,T,D]
    gemm_mfma<1><<<dim3(3 * C_ / 128, MT / 128), 256, 0, stream>>>(
        xb, Wqt, bqkv, nullptr, q, k, v, (int)MT, 3 * C_, C_);

    // 2) routing path (fp32)
    chunk_mean_kernel<<<B_ * NCH, 256, 0, stream>>>(x, cm);
    rowgemm32<<<(B_ * NCH + 7) / 8, 256, 0, stream>>>(cm, Wrouter, brouter, emb_out, B_ * NCH, 0);
    l2norm_rows<<<(B_ * NCH + 7) / 8, 256, 0, stream>>>(emb_out, ren, B_ * NCH);
    rowgemm32<<<((int)MT + 7) / 8, 256, 0, stream>>>(x, Wq_rt, bq_rt, qrt, (int)MT, 1);
    scores_topk<<<((int)MT + 255) / 256, 256, 0, stream>>>(qrt, ren, sc_out, idx_out);

    // 3) MFMA flash attention -> bf16 ya [B,T,C]
    attn_mfma<<<dim3(1024), 256, 0, stream>>>(q, k, v, yab);

    // 4) output projection (MFMA) -> f32 y
    gemm_mfma<0><<<dim3(C_ / 128, MT / 128), 256, 0, stream>>>(
        yab, Wpt, bproj, y_out, nullptr, nullptr, nullptr, (int)MT, C_, C_);
}